// Round 9
// baseline (220.282 us; speedup 1.0000x reference)
//
#include <hip/hip_runtime.h>
#include <hip/hip_bf16.h>
#include <math.h>

typedef __hip_bfloat16 bf16;
typedef __attribute__((ext_vector_type(8))) short short8;
typedef __attribute__((ext_vector_type(4))) short short4v;
typedef __attribute__((ext_vector_type(4))) float f32x4;
typedef __attribute__((ext_vector_type(4))) unsigned int u32x4;

#define NSEQ 2304
#define CDIM 256
#define NHD  4
#define DH   64

#if __has_builtin(__builtin_amdgcn_exp2f)
#define EXP2F __builtin_amdgcn_exp2f
#else
#define EXP2F exp2f
#endif

static __device__ __forceinline__ f32x4 mfma_bf16(short8 a, short8 b, f32x4 c) {
  return __builtin_amdgcn_mfma_f32_16x16x32_bf16(a, b, c, 0, 0, 0);
}
static __device__ __forceinline__ short8 ld8(const bf16* p) {
  return *reinterpret_cast<const short8*>(p);
}
static __device__ __forceinline__ short8 lds8(const bf16* p) {
  return *reinterpret_cast<const short8*>(p);
}
static __device__ __forceinline__ float b2f(short v) {
  unsigned int u = ((unsigned int)(unsigned short)v) << 16;
  return __uint_as_float(u);
}
static __device__ __forceinline__ short f2b(float f) {
  bf16 h = __float2bfloat16(f);
  return *reinterpret_cast<short*>(&h);
}
// XOR-swizzled LDS byte offset: 128B rows (row contributes 0 banks), 16B
// slots XORed by row&7 (guide G4 attention-K fix). Bijective slot
// permutation applied identically at write and read.
static __device__ __forceinline__ int swzb(int row, int off) {
  return (row << 7) + (off ^ ((row & 7) << 4));
}

// ---------------- dtype probe ----------------
__global__ __launch_bounds__(256) void detect_kernel(const void* __restrict__ xraw,
                                                     int* __restrict__ flag) {
  int t = threadIdx.x;
  const unsigned short* s = (const unsigned short*)xraw;
  int bad = 0;
#pragma unroll
  for (int i = 0; i < 8; ++i) {
    unsigned idx = (((unsigned)(t * 8 + i)) * 9173u) & ((1u << 20) - 1);
    unsigned short v = s[idx * 2];
    unsigned e = (v >> 7) & 0xFFu;
    if (e > 133u) bad++;
  }
  __shared__ int tot;
  if (t == 0) tot = 0;
  __syncthreads();
  atomicAdd(&tot, bad);
  __syncthreads();
  if (t == 0) flag[0] = (tot >= 16) ? 1 : 0;
}

// ---------------- fused conversion of all float inputs ----------------
__global__ __launch_bounds__(256) void cvt_all_kernel(const void* sx, const void* sqkv, const void* sproj,
                                                      const void* sw1, const void* sw2,
                                                      const void* g1, const void* b1, const void* g2,
                                                      const void* b2, const void* bias1, const void* bias2,
                                                      bf16* dx, bf16* dqkv, bf16* dproj,
                                                      bf16* dw1, bf16* dw2, bf16* dsm,
                                                      const int* __restrict__ flag) {
  int is32 = flag[0];
  int bid = blockIdx.x;
  const void* src; bf16* dst; int i4;
  if (bid < 2304)      { src = sx;    dst = dx;    i4 = bid * 256 + threadIdx.x; }
  else if (bid < 2496) { src = sqkv;  dst = dqkv;  i4 = (bid - 2304) * 256 + threadIdx.x; }
  else if (bid < 2560) { src = sproj; dst = dproj; i4 = (bid - 2496) * 256 + threadIdx.x; }
  else if (bid < 2816) { src = sw1;   dst = dw1;   i4 = (bid - 2560) * 256 + threadIdx.x; }
  else if (bid < 3072) { src = sw2;   dst = dw2;   i4 = (bid - 2816) * 256 + threadIdx.x; }
  else {
    const void* srcs[6] = {g1, b1, g2, b2, bias1, bias2};
    const int ns[6] = {256, 256, 256, 256, 1024, 256};
    const int off[6] = {0, 256, 512, 768, 1024, 2048};
    int t = threadIdx.x;
#pragma unroll
    for (int j = 0; j < 6; ++j)
      for (int i = t; i < ns[j]; i += 256) {
        if (is32) dsm[off[j] + i] = __float2bfloat16(((const float*)srcs[j])[i]);
        else      dsm[off[j] + i] = ((const bf16*)srcs[j])[i];
      }
    return;
  }
  if (is32) {
    float4 v = ((const float4*)src)[i4];
    short4v o;
    o[0] = f2b(v.x); o[1] = f2b(v.y); o[2] = f2b(v.z); o[3] = f2b(v.w);
    ((short4v*)dst)[i4] = o;
  } else {
    ((short4v*)dst)[i4] = ((const short4v*)src)[i4];
  }
}

// ---------------- QKV GEMM with FUSED RoPE epilogue (r13-validated) ----------------
__global__ __launch_bounds__(256, 1) void qkv_kernel(const bf16* __restrict__ X,
                                                     const bf16* __restrict__ Wqkv,
                                                     bf16* __restrict__ Q, bf16* __restrict__ K,
                                                     bf16* __restrict__ Vt,
                                                     const int* __restrict__ Wp) {
  int wave = threadIdx.x >> 6, lane = threadIdx.x & 63;
  int l15 = lane & 15, quad = lane >> 4;
  int m0 = (blockIdx.x * 4 + wave) * 64;
  int n0 = blockIdx.y * 64;
  const bf16* arow = X + (size_t)(m0 + l15) * CDIM + quad * 8;
  const bf16* brow = Wqkv + (size_t)(n0 + l15) * CDIM + quad * 8;
  f32x4 z = {0.f, 0.f, 0.f, 0.f};
  f32x4 acc[4][4];
#pragma unroll
  for (int j = 0; j < 4; ++j)
#pragma unroll
    for (int i = 0; i < 4; ++i) acc[j][i] = z;

  short8 a[4], b[4];
#pragma unroll
  for (int i = 0; i < 4; ++i) a[i] = ld8(arow + (size_t)i * 16 * CDIM);
#pragma unroll
  for (int j = 0; j < 4; ++j) b[j] = ld8(brow + (size_t)j * 16 * CDIM);
#pragma unroll
  for (int kk = 32; kk <= CDIM; kk += 32) {
    short8 an[4], bn[4];
    if (kk < CDIM) {
#pragma unroll
      for (int i = 0; i < 4; ++i) an[i] = ld8(arow + (size_t)i * 16 * CDIM + kk);
#pragma unroll
      for (int j = 0; j < 4; ++j) bn[j] = ld8(brow + (size_t)j * 16 * CDIM + kk);
    }
#pragma unroll
    for (int j = 0; j < 4; ++j)
#pragma unroll
      for (int i = 0; i < 4; ++i) acc[j][i] = mfma_bf16(b[j], a[i], acc[j][i]);
    if (kk < CDIM) {
#pragma unroll
      for (int i = 0; i < 4; ++i) a[i] = an[i];
#pragma unroll
      for (int j = 0; j < 4; ++j) b[j] = bn[j];
    }
  }

  int which = n0 >> 8, h = (n0 & 255) >> 6;
  if (which == 2) {
#pragma unroll
    for (int j = 0; j < 4; ++j) {
      int d0 = j * 16 + quad * 4;
#pragma unroll
      for (int i = 0; i < 4; ++i) {
        int gm = m0 + i * 16 + l15;
        int bb = gm / NSEQ, n = gm % NSEQ;
        int bh = bb * NHD + h;
#pragma unroll
        for (int r = 0; r < 4; ++r)
          Vt[((size_t)bh * DH + d0 + r) * NSEQ + n] = __float2bfloat16(acc[j][i][r]);
      }
    }
  } else {
    int Wv = Wp[0];
    if (Wv <= 0 || Wv > 65536) Wv = 48;
    bf16* dst = (which == 0) ? Q : K;
    const float cc = -0.28782313662425574f;  // -ln(10000)/32
    const float EC1 = 0.7498942434f, EC2 = 0.5623413252f, EC3 = 0.4216965034f;
#pragma unroll
    for (int i = 0; i < 4; ++i) {
      int gm = m0 + i * 16 + l15;
      int bb = gm / NSEQ, n = gm % NSEQ;
      int bh = bb * NHD + h;
      int py = n / Wv, px = n - py * Wv;
#pragma unroll
      for (int j = 0; j < 4; ++j) {
        int d0 = j * 16 + quad * 4;
        float pos = (d0 & 32) ? (float)px : (float)py;
        int base = d0 & 31;
        float fb = __expf(cc * (float)base);
        float f0 = fb, f1 = fb * EC1, f2 = fb * EC2, f3 = fb * EC3;
        float s0, c0, s1, c1, s2, c2, s3, c3;
        __sincosf(pos * f0, &s0, &c0);
        __sincosf(pos * f1, &s1, &c1);
        __sincosf(pos * f2, &s2, &c2);
        __sincosf(pos * f3, &s3, &c3);
        float a0 = acc[j][i][0], a1 = acc[j][i][1], a2 = acc[j][i][2], a3 = acc[j][i][3];
        short4v ov;
        ov[0] = f2b(a0 * c0 - a1 * s0);
        ov[1] = f2b(a1 * c1 + a0 * s1);
        ov[2] = f2b(a2 * c2 - a3 * s2);
        ov[3] = f2b(a3 * c3 + a2 * s3);
        *reinterpret_cast<short4v*>(dst + ((size_t)bh * NSEQ + n) * DH + d0) = ov;
      }
    }
  }
}

// ---------------- FC1: qkv-style no-LDS GEMM + bias + GELU ----------------
// FC1 (M=9216, N=1024, K=256) was latency-bound in the gemm128 LDS
// structure (r8 profile: 50us, MfmaUtil 3.3%, all pipes idle). Operands are
// L2-resident (F 4.7MB + W1 0.5MB), so LDS staging bought only barrier
// serialization (common-mistake #7). This is the validated qkv GEMM core
// verbatim (per-wave register double-buffer, no LDS, no barriers) with a
// bias+GELU epilogue.
__global__ __launch_bounds__(256, 1) void fc1_kernel(const bf16* __restrict__ A,
                                                     const bf16* __restrict__ Wm,
                                                     const bf16* __restrict__ bias,
                                                     bf16* __restrict__ outp) {
  int wave = threadIdx.x >> 6, lane = threadIdx.x & 63;
  int l15 = lane & 15, quad = lane >> 4;
  int m0 = (blockIdx.x * 4 + wave) * 64;
  int n0 = blockIdx.y * 64;
  const bf16* arow = A + (size_t)(m0 + l15) * CDIM + quad * 8;
  const bf16* brow = Wm + (size_t)(n0 + l15) * CDIM + quad * 8;
  f32x4 z = {0.f, 0.f, 0.f, 0.f};
  f32x4 acc[4][4];
#pragma unroll
  for (int j = 0; j < 4; ++j)
#pragma unroll
    for (int i = 0; i < 4; ++i) acc[j][i] = z;

  short8 a[4], b[4];
#pragma unroll
  for (int i = 0; i < 4; ++i) a[i] = ld8(arow + (size_t)i * 16 * CDIM);
#pragma unroll
  for (int j = 0; j < 4; ++j) b[j] = ld8(brow + (size_t)j * 16 * CDIM);
#pragma unroll
  for (int kk = 32; kk <= CDIM; kk += 32) {
    short8 an[4], bn[4];
    if (kk < CDIM) {
#pragma unroll
      for (int i = 0; i < 4; ++i) an[i] = ld8(arow + (size_t)i * 16 * CDIM + kk);
#pragma unroll
      for (int j = 0; j < 4; ++j) bn[j] = ld8(brow + (size_t)j * 16 * CDIM + kk);
    }
#pragma unroll
    for (int j = 0; j < 4; ++j)
#pragma unroll
      for (int i = 0; i < 4; ++i) acc[j][i] = mfma_bf16(b[j], a[i], acc[j][i]);
    if (kk < CDIM) {
#pragma unroll
      for (int i = 0; i < 4; ++i) a[i] = an[i];
#pragma unroll
      for (int j = 0; j < 4; ++j) b[j] = bn[j];
    }
  }

  // epilogue: bias + exact GELU, store bf16
#pragma unroll
  for (int j = 0; j < 4; ++j) {
    int col0 = n0 + j * 16 + quad * 4;
    short4v bl = *reinterpret_cast<const short4v*>(bias + col0);
    float bb4[4];
#pragma unroll
    for (int r = 0; r < 4; ++r) bb4[r] = b2f(bl[r]);
#pragma unroll
    for (int i = 0; i < 4; ++i) {
      int row = m0 + i * 16 + l15;
      short4v ov;
#pragma unroll
      for (int r = 0; r < 4; ++r) {
        float hv = acc[j][i][r] + bb4[r];
        ov[r] = f2b(0.5f * hv * (1.f + erff(hv * 0.70710678118f)));
      }
      *reinterpret_cast<short4v*>(outp + (size_t)row * 1024 + col0) = ov;
    }
  }
}

// ---------------- Flash attention (r8-validated: K-split + swizzled LDS) ----------------
__global__ __launch_bounds__(256, 4) void attn_kernel(const bf16* __restrict__ Q, const bf16* __restrict__ K,
                                                      const bf16* __restrict__ Vt, bf16* __restrict__ AO) {
  int bh = blockIdx.x, qt = blockIdx.y;
  int tid = threadIdx.x;
  int wave = tid >> 6, lane = tid & 63;
  int l15 = lane & 15, quad = lane >> 4;
  int qf = wave & 1;   // q half: rows [qf*32, qf*32+32)
  int ks = wave >> 1;  // k slice: cols [ks*32, ks*32+32) of each 64-tile
  int m0 = qt * 64 + qf * 32;
  const bf16* Qb = Q + (size_t)bh * NSEQ * DH;
  const bf16* Kb = K + (size_t)bh * NSEQ * DH;
  const bf16* Vb = Vt + (size_t)bh * DH * NSEQ;

  // [0,8K)+[8K,16K) = K double-buffer; [16K,24K)+[24K,32K) = V double-buffer.
  __shared__ __align__(16) char smem[32768];

  // staging: 256 threads cover 512 16B slots per tile (2 K + 2 V each)
  int r1 = tid >> 3, c1b = (tid & 7) * 16;   // row, byte slot
  int r1b = r1 + 32;

  // Q pre-scaled by 0.125 * log2(e) so p = exp2(s) directly
  const float QS = 0.18033688011112042f;
  short8 qa0 = ld8(Qb + (size_t)(m0 + l15) * DH + quad * 8);
  short8 qa1 = ld8(Qb + (size_t)(m0 + l15) * DH + 32 + quad * 8);
  short8 qb0 = ld8(Qb + (size_t)(m0 + 16 + l15) * DH + quad * 8);
  short8 qb1 = ld8(Qb + (size_t)(m0 + 16 + l15) * DH + 32 + quad * 8);
#pragma unroll
  for (int i = 0; i < 8; ++i) {
    qa0[i] = f2b(b2f(qa0[i]) * QS);
    qa1[i] = f2b(b2f(qa1[i]) * QS);
    qb0[i] = f2b(b2f(qb0[i]) * QS);
    qb1[i] = f2b(b2f(qb1[i]) * QS);
  }

  f32x4 z = {0.f, 0.f, 0.f, 0.f};
  f32x4 o[4] = {z, z, z, z};
  f32x4 o2[4] = {z, z, z, z};
  float l_run = 0.f, l_run2 = 0.f;

  // stage K/V tile 0
  *reinterpret_cast<short8*>(smem + swzb(r1, c1b))          = ld8(Kb + (size_t)r1 * DH + c1b / 2);
  *reinterpret_cast<short8*>(smem + swzb(r1b, c1b))         = ld8(Kb + (size_t)r1b * DH + c1b / 2);
  *reinterpret_cast<short8*>(smem + 16384 + swzb(r1, c1b))  = ld8(Vb + (size_t)r1 * NSEQ + c1b / 2);
  *reinterpret_cast<short8*>(smem + 16384 + swzb(r1b, c1b)) = ld8(Vb + (size_t)r1b * NSEQ + c1b / 2);
  __syncthreads();

  for (int it = 0; it < NSEQ / 64; ++it) {
    int cur = it & 1;
    bool more = (it + 1 < NSEQ / 64);

    // prefetch next K/V tile into registers (global)
    short8 kpA, kpB, vpA, vpB;
    if (more) {
      int kn = (it + 1) * 64;
      kpA = ld8(Kb + (size_t)(kn + r1) * DH + c1b / 2);
      kpB = ld8(Kb + (size_t)(kn + r1b) * DH + c1b / 2);
      vpA = ld8(Vb + (size_t)r1 * NSEQ + kn + c1b / 2);
      vpB = ld8(Vb + (size_t)r1b * NSEQ + kn + c1b / 2);
    }

    const char* kb = smem + cur * 8192;
    const char* vb = smem + 16384 + cur * 8192;

    // QK^T for this wave's 32 k-rows x 32 q-rows
    f32x4 s[2], s2[2];
#pragma unroll
    for (int kt = 0; kt < 2; ++kt) {
      int krow = ks * 32 + kt * 16 + l15;
      short8 kf0 = *reinterpret_cast<const short8*>(kb + swzb(krow, quad * 16));
      short8 kf1 = *reinterpret_cast<const short8*>(kb + swzb(krow, quad * 16 + 64));
      s[kt] = mfma_bf16(kf0, qa0, z);
      s[kt] = mfma_bf16(kf1, qa1, s[kt]);
      s2[kt] = mfma_bf16(kf0, qb0, z);
      s2[kt] = mfma_bf16(kf1, qb1, s2[kt]);
    }

    // exp2 + in-register P->B-frag redistribution (no LDS)
    unsigned int A0, B0, A1, B1, C0, D0, C1, D1;
    {
      float p00 = EXP2F(s[0][0]), p01 = EXP2F(s[0][1]), p02 = EXP2F(s[0][2]), p03 = EXP2F(s[0][3]);
      float p10 = EXP2F(s[1][0]), p11 = EXP2F(s[1][1]), p12 = EXP2F(s[1][2]), p13 = EXP2F(s[1][3]);
      l_run += ((p00 + p01) + (p02 + p03)) + ((p10 + p11) + (p12 + p13));
      asm("v_cvt_pk_bf16_f32 %0, %1, %2" : "=v"(A0) : "v"(p00), "v"(p01));
      asm("v_cvt_pk_bf16_f32 %0, %1, %2" : "=v"(B0) : "v"(p02), "v"(p03));
      asm("v_cvt_pk_bf16_f32 %0, %1, %2" : "=v"(A1) : "v"(p10), "v"(p11));
      asm("v_cvt_pk_bf16_f32 %0, %1, %2" : "=v"(B1) : "v"(p12), "v"(p13));
      float q00 = EXP2F(s2[0][0]), q01 = EXP2F(s2[0][1]), q02 = EXP2F(s2[0][2]), q03 = EXP2F(s2[0][3]);
      float q10 = EXP2F(s2[1][0]), q11 = EXP2F(s2[1][1]), q12 = EXP2F(s2[1][2]), q13 = EXP2F(s2[1][3]);
      l_run2 += ((q00 + q01) + (q02 + q03)) + ((q10 + q11) + (q12 + q13));
      asm("v_cvt_pk_bf16_f32 %0, %1, %2" : "=v"(C0) : "v"(q00), "v"(q01));
      asm("v_cvt_pk_bf16_f32 %0, %1, %2" : "=v"(D0) : "v"(q02), "v"(q03));
      asm("v_cvt_pk_bf16_f32 %0, %1, %2" : "=v"(C1) : "v"(q10), "v"(q11));
      asm("v_cvt_pk_bf16_f32 %0, %1, %2" : "=v"(D1) : "v"(q12), "v"(q13));
    }
    asm("v_permlane32_swap_b32 %0, %1" : "+v"(A0), "+v"(A1));
    asm("v_permlane16_swap_b32 %0, %1" : "+v"(A0), "+v"(A1));
    asm("v_permlane32_swap_b32 %0, %1" : "+v"(B0), "+v"(B1));
    asm("v_permlane16_swap_b32 %0, %1" : "+v"(B0), "+v"(B1));
    asm("v_permlane32_swap_b32 %0, %1" : "+v"(C0), "+v"(C1));
    asm("v_permlane16_swap_b32 %0, %1" : "+v"(C0), "+v"(C1));
    asm("v_permlane32_swap_b32 %0, %1" : "+v"(D0), "+v"(D1));
    asm("v_permlane16_swap_b32 %0, %1" : "+v"(D0), "+v"(D1));

    u32x4 wA; wA[0] = A0; wA[1] = B0; wA[2] = A1; wA[3] = B1;
    u32x4 wB; wB[0] = C0; wB[1] = D0; wB[2] = C1; wB[3] = D1;
    short8 pfA = *reinterpret_cast<short8*>(&wA);
    short8 pfB = *reinterpret_cast<short8*>(&wB);

    // PV for this wave's 32 k-cols (partial o over the k-slice)
#pragma unroll
    for (int t = 0; t < 4; ++t) {
      short8 vf = *reinterpret_cast<const short8*>(vb + swzb(t * 16 + l15, ks * 64 + quad * 16));
      o[t] = mfma_bf16(vf, pfA, o[t]);
      o2[t] = mfma_bf16(vf, pfB, o2[t]);
    }

    if (more) {
      char* kn_ = smem + (1 - cur) * 8192;
      char* vn_ = smem + 16384 + (1 - cur) * 8192;
      *reinterpret_cast<short8*>(kn_ + swzb(r1, c1b))  = kpA;
      *reinterpret_cast<short8*>(kn_ + swzb(r1b, c1b)) = kpB;
      *reinterpret_cast<short8*>(vn_ + swzb(r1, c1b))  = vpA;
      *reinterpret_cast<short8*>(vn_ + swzb(r1b, c1b)) = vpB;
    }
    __syncthreads();
  }

  // ---- cross-kslice combine via LDS scratch (smem is dead now) ----
  float* scr = (float*)smem;
  int slot = qf * 64 + lane;  // wave2 pairs wave0 (qf=0), wave3 pairs wave1
  if (ks == 1) {
    float* p = scr + slot * 36;
#pragma unroll
    for (int t = 0; t < 4; ++t) {
      *reinterpret_cast<f32x4*>(p + t * 4) = o[t];
      *reinterpret_cast<f32x4*>(p + 16 + t * 4) = o2[t];
    }
    p[32] = l_run;
    p[33] = l_run2;
  }
  __syncthreads();
  if (ks == 0) {
    float* p = scr + slot * 36;
#pragma unroll
    for (int t = 0; t < 4; ++t) {
      f32x4 pa = *reinterpret_cast<f32x4*>(p + t * 4);
      f32x4 pb2 = *reinterpret_cast<f32x4*>(p + 16 + t * 4);
#pragma unroll
      for (int r = 0; r < 4; ++r) {
        o[t][r] += pa[r];
        o2[t][r] += pb2[r];
      }
    }
    l_run += p[32];
    l_run2 += p[33];

    l_run += __shfl_xor(l_run, 16);
    l_run += __shfl_xor(l_run, 32);
    l_run2 += __shfl_xor(l_run2, 16);
    l_run2 += __shfl_xor(l_run2, 32);
    float inv = 1.f / l_run;
    float inv2 = 1.f / l_run2;
    int b = bh >> 2, h = bh & 3;
    bf16* orow = AO + ((size_t)b * NSEQ + (m0 + l15)) * CDIM + h * DH;
    bf16* orow2 = AO + ((size_t)b * NSEQ + (m0 + 16 + l15)) * CDIM + h * DH;
#pragma unroll
    for (int t = 0; t < 4; ++t) {
      short4v ov, ov2;
#pragma unroll
      for (int r = 0; r < 4; ++r) {
        ov[r] = f2b(o[t][r] * inv);
        ov2[r] = f2b(o2[t][r] * inv2);
      }
      *reinterpret_cast<short4v*>(orow + t * 16 + quad * 4) = ov;
      *reinterpret_cast<short4v*>(orow2 + t * 16 + quad * 4) = ov2;
    }
  }
}

// ---------------- GEMM (NC=256) with residual + FUSED LayerNorm epilogue ----------------
template <int KD, int HASBIAS, int FINAL>
__global__ __launch_bounds__(256) void gemm_ln(const bf16* __restrict__ A, const bf16* __restrict__ Wm,
                                               const bf16* __restrict__ bias, const bf16* __restrict__ res,
                                               const bf16* __restrict__ g, const bf16* __restrict__ bv,
                                               void* __restrict__ outp, const int* __restrict__ flag) {
  constexpr int KS = KD / 32;
  int tid = threadIdx.x;
  int wave = tid >> 6, lane = tid & 63;
  int l15 = lane & 15, quad = lane >> 4;
  int wn = wave * 64;
  int m0 = blockIdx.x * 32;
  int is32 = FINAL ? flag[0] : 0;

  __shared__ __align__(16) bf16 abuf[2][32 * 40];
  __shared__ __align__(16) bf16 bbuf[2][256 * 40];
  __shared__ float red[4][32][2];

  int sr = tid >> 2, sc = (tid & 3) * 8;      // B: rows sr+u*64, u=0..3
  bool doA = tid < 128;
  int ra = tid >> 2, ca = (tid & 3) * 8;      // A: rows 0..31 (tid<128)

  const bf16* ag = A + (size_t)(m0 + ra) * KD + ca;
  const bf16* bg[4];
#pragma unroll
  for (int u = 0; u < 4; ++u) bg[u] = Wm + (size_t)(sr + u * 64) * KD + sc;

  f32x4 z = {0.f, 0.f, 0.f, 0.f};
  f32x4 acc[4][2];
#pragma unroll
  for (int j = 0; j < 4; ++j)
#pragma unroll
    for (int i = 0; i < 2; ++i) acc[j][i] = z;

  if (doA) *reinterpret_cast<short8*>(abuf[0] + ra * 40 + ca) = ld8(ag);
#pragma unroll
  for (int u = 0; u < 4; ++u)
    *reinterpret_cast<short8*>(bbuf[0] + (sr + u * 64) * 40 + sc) = ld8(bg[u]);
  __syncthreads();

  for (int s = 0; s < KS; ++s) {
    int cur = s & 1;
    bool more = (s + 1 < KS);
    short8 anx, bnx[4];
    if (more) {
      if (doA) anx = ld8(ag + (s + 1) * 32);
#pragma unroll
      for (int u = 0; u < 4; ++u) bnx[u] = ld8(bg[u] + (s + 1) * 32);
    }
    short8 af[2], bf_[4];
#pragma unroll
    for (int i = 0; i < 2; ++i)
      af[i] = lds8(abuf[cur] + (size_t)(i * 16 + l15) * 40 + quad * 8);
#pragma unroll
    for (int j = 0; j < 4; ++j)
      bf_[j] = lds8(bbuf[cur] + (size_t)(wn + j * 16 + l15) * 40 + quad * 8);
#pragma unroll
    for (int j = 0; j < 4; ++j)
#pragma unroll
      for (int i = 0; i < 2; ++i)
        acc[j][i] = mfma_bf16(bf_[j], af[i], acc[j][i]);
    if (more) {
      if (doA) *reinterpret_cast<short8*>(abuf[1 - cur] + ra * 40 + ca) = anx;
#pragma unroll
      for (int u = 0; u < 4; ++u)
        *reinterpret_cast<short8*>(bbuf[1 - cur] + (sr + u * 64) * 40 + sc) = bnx[u];
    }
    __syncthreads();
  }

  // ---- epilogue: bias + residual, then fused LayerNorm over the full row ----
  float bb[4][4];
  if (HASBIAS) {
#pragma unroll
    for (int j = 0; j < 4; ++j) {
      short4v bl = *reinterpret_cast<const short4v*>(bias + wn + j * 16 + quad * 4);
#pragma unroll
      for (int r = 0; r < 4; ++r) bb[j][r] = b2f(bl[r]);
    }
  }
  float vals[2][4][4];
  float s0 = 0.f, q0 = 0.f, s1 = 0.f, q1 = 0.f;
#pragma unroll
  for (int i = 0; i < 2; ++i) {
    int row = m0 + i * 16 + l15;
#pragma unroll
    for (int j = 0; j < 4; ++j) {
      int col0 = wn + j * 16 + quad * 4;
      short4v rl = *reinterpret_cast<const short4v*>(res + (size_t)row * CDIM + col0);
#pragma unroll
      for (int r = 0; r < 4; ++r) {
        float v = acc[j][i][r] + (HASBIAS ? bb[j][r] : 0.f) + b2f(rl[r]);
        vals[i][j][r] = v;
        if (i == 0) { s0 += v; q0 += v * v; }
        else        { s1 += v; q1 += v * v; }
      }
    }
  }
  s0 += __shfl_xor(s0, 16); s0 += __shfl_xor(s0, 32);
  q0 += __shfl_xor(q0, 16); q0 += __shfl_xor(q0, 32);
  s1 += __shfl_xor(s1, 16); s1 += __shfl_xor(s1, 32);
  q1 += __shfl_xor(q1, 16); q1 += __shfl_xor(q1, 32);
  if (quad == 0) {
    red[wave][l15][0] = s0;      red[wave][l15][1] = q0;
    red[wave][16 + l15][0] = s1; red[wave][16 + l15][1] = q1;
  }
  __syncthreads();

#pragma unroll
  for (int i = 0; i < 2; ++i) {
    int rl_ = i * 16 + l15;
    float S = 0.f, Q = 0.f;
#pragma unroll
    for (int w = 0; w < 4; ++w) { S += red[w][rl_][0]; Q += red[w][rl_][1]; }
    float mu = S * (1.f / CDIM);
    float var = Q * (1.f / CDIM) - mu * mu;
    float rstd = rsqrtf(var + 1e-5f);
    int row = m0 + i * 16 + l15;
#pragma unroll
    for (int j = 0; j < 4; ++j) {
      int col0 = wn + j * 16 + quad * 4;
      short4v gl = *reinterpret_cast<const short4v*>(g + col0);
      short4v bl2 = *reinterpret_cast<const short4v*>(bv + col0);
      size_t idx = (size_t)row * CDIM + col0;
      if (FINAL && is32) {
        float4 ov;
        ov.x = (vals[i][j][0] - mu) * rstd * b2f(gl[0]) + b2f(bl2[0]);
        ov.y = (vals[i][j][1] - mu) * rstd * b2f(gl[1]) + b2f(bl2[1]);
        ov.z = (vals[i][j][2] - mu) * rstd * b2f(gl[2]) + b2f(bl2[2]);
        ov.w = (vals[i][j][3] - mu) * rstd * b2f(gl[3]) + b2f(bl2[3]);
        *reinterpret_cast<float4*>((float*)outp + idx) = ov;
      } else {
        short4v ov;
#pragma unroll
        for (int r = 0; r < 4; ++r)
          ov[r] = f2b((vals[i][j][r] - mu) * rstd * b2f(gl[r]) + b2f(bl2[r]));
        *reinterpret_cast<short4v*>((bf16*)outp + idx) = ov;
      }
    }
  }
}

extern "C" void kernel_launch(void* const* d_in, const int* in_sizes, int n_in,
                              void* d_out, int out_size, void* d_ws, size_t ws_size,
                              hipStream_t stream) {
  const int* Wp = (const int*)d_in[12];

  char* ws = (char*)d_ws;
  const size_t SZ = 4718592;  // 2304*4*256 bf16 bytes
  bf16* Qc  = (bf16*)(ws + 0 * SZ);
  bf16* Kc  = (bf16*)(ws + 1 * SZ);
  bf16* Vt  = (bf16*)(ws + 2 * SZ);
  bf16* AO  = (bf16*)(ws + 3 * SZ);
  bf16* F   = (bf16*)(ws + 4 * SZ);
  bf16* xc  = (bf16*)(ws + 6 * SZ);
  bf16* G   = (bf16*)(ws + 0);              // overlays Qc..AO (4*SZ exactly)
  bf16* Wqkvc  = (bf16*)(ws + 7 * SZ);
  bf16* Wprojc = (bf16*)(ws + 7 * SZ + 393216);
  bf16* W1c    = (bf16*)(ws + 7 * SZ + 524288);
  bf16* W2c    = (bf16*)(ws + 7 * SZ + 1048576);
  bf16* smallc = (bf16*)(ws + 7 * SZ + 1572864);
  bf16* g1c  = smallc + 0;
  bf16* b1c  = smallc + 256;
  bf16* g2c  = smallc + 512;
  bf16* b2c  = smallc + 768;
  bf16* bf1c = smallc + 1024;
  bf16* bf2c = smallc + 2048;
  int*  flagp = (int*)(ws + 7 * SZ + 1581568);

  detect_kernel<<<1, 256, 0, stream>>>(d_in[0], flagp);
  cvt_all_kernel<<<3073, 256, 0, stream>>>(d_in[0], d_in[1], d_in[2], d_in[7], d_in[9],
                                           d_in[3], d_in[4], d_in[5], d_in[6], d_in[8], d_in[10],
                                           xc, Wqkvc, Wprojc, W1c, W2c, smallc, flagp);

  qkv_kernel<<<dim3(36, 12), 256, 0, stream>>>(xc, Wqkvc, Qc, Kc, Vt, Wp);
  attn_kernel<<<dim3(16, 36), 256, 0, stream>>>(Qc, Kc, Vt, AO);
  // proj + residual + LN1 -> F (bf16)
  gemm_ln<256, 0, 0><<<288, 256, 0, stream>>>(AO, Wprojc, nullptr, xc, g1c, b1c, F, flagp);
  // FC1 + bias + GELU -> G (qkv-style no-LDS GEMM)
  fc1_kernel<<<dim3(36, 16), 256, 0, stream>>>(F, W1c, bf1c, G);
  // FC2 + bias + residual(F) + LN2 -> d_out (flag dtype)
  gemm_ln<1024, 1, 1><<<288, 256, 0, stream>>>(G, W2c, bf2c, F, g2c, b2c, d_out, flagp);
}

// Round 10
// 205.278 us; speedup vs baseline: 1.0731x; 1.0731x over previous
//
#include <hip/hip_runtime.h>
#include <hip/hip_bf16.h>
#include <math.h>

typedef __hip_bfloat16 bf16;
typedef __attribute__((ext_vector_type(8))) short short8;
typedef __attribute__((ext_vector_type(4))) short short4v;
typedef __attribute__((ext_vector_type(4))) float f32x4;
typedef __attribute__((ext_vector_type(4))) unsigned int u32x4;

#define NSEQ 2304
#define CDIM 256
#define NHD  4
#define DH   64

#if __has_builtin(__builtin_amdgcn_exp2f)
#define EXP2F __builtin_amdgcn_exp2f
#else
#define EXP2F exp2f
#endif

static __device__ __forceinline__ f32x4 mfma_bf16(short8 a, short8 b, f32x4 c) {
  return __builtin_amdgcn_mfma_f32_16x16x32_bf16(a, b, c, 0, 0, 0);
}
static __device__ __forceinline__ short8 ld8(const bf16* p) {
  return *reinterpret_cast<const short8*>(p);
}
static __device__ __forceinline__ short8 lds8(const bf16* p) {
  return *reinterpret_cast<const short8*>(p);
}
static __device__ __forceinline__ float b2f(short v) {
  unsigned int u = ((unsigned int)(unsigned short)v) << 16;
  return __uint_as_float(u);
}
static __device__ __forceinline__ short f2b(float f) {
  bf16 h = __float2bfloat16(f);
  return *reinterpret_cast<short*>(&h);
}
// XOR-swizzled LDS byte offset (r8-validated attn LDS map).
static __device__ __forceinline__ int swzb(int row, int off) {
  return (row << 7) + (off ^ ((row & 7) << 4));
}

// ---------------- dtype probe ----------------
__global__ __launch_bounds__(256) void detect_kernel(const void* __restrict__ xraw,
                                                     int* __restrict__ flag) {
  int t = threadIdx.x;
  const unsigned short* s = (const unsigned short*)xraw;
  int bad = 0;
#pragma unroll
  for (int i = 0; i < 8; ++i) {
    unsigned idx = (((unsigned)(t * 8 + i)) * 9173u) & ((1u << 20) - 1);
    unsigned short v = s[idx * 2];
    unsigned e = (v >> 7) & 0xFFu;
    if (e > 133u) bad++;
  }
  __shared__ int tot;
  if (t == 0) tot = 0;
  __syncthreads();
  atomicAdd(&tot, bad);
  __syncthreads();
  if (t == 0) flag[0] = (tot >= 16) ? 1 : 0;
}

// ---------------- fused conversion of all float inputs ----------------
__global__ __launch_bounds__(256) void cvt_all_kernel(const void* sx, const void* sqkv, const void* sproj,
                                                      const void* sw1, const void* sw2,
                                                      const void* g1, const void* b1, const void* g2,
                                                      const void* b2, const void* bias1, const void* bias2,
                                                      bf16* dx, bf16* dqkv, bf16* dproj,
                                                      bf16* dw1, bf16* dw2, bf16* dsm,
                                                      const int* __restrict__ flag) {
  int is32 = flag[0];
  int bid = blockIdx.x;
  const void* src; bf16* dst; int i4;
  if (bid < 2304)      { src = sx;    dst = dx;    i4 = bid * 256 + threadIdx.x; }
  else if (bid < 2496) { src = sqkv;  dst = dqkv;  i4 = (bid - 2304) * 256 + threadIdx.x; }
  else if (bid < 2560) { src = sproj; dst = dproj; i4 = (bid - 2496) * 256 + threadIdx.x; }
  else if (bid < 2816) { src = sw1;   dst = dw1;   i4 = (bid - 2560) * 256 + threadIdx.x; }
  else if (bid < 3072) { src = sw2;   dst = dw2;   i4 = (bid - 2816) * 256 + threadIdx.x; }
  else {
    const void* srcs[6] = {g1, b1, g2, b2, bias1, bias2};
    const int ns[6] = {256, 256, 256, 256, 1024, 256};
    const int off[6] = {0, 256, 512, 768, 1024, 2048};
    int t = threadIdx.x;
#pragma unroll
    for (int j = 0; j < 6; ++j)
      for (int i = t; i < ns[j]; i += 256) {
        if (is32) dsm[off[j] + i] = __float2bfloat16(((const float*)srcs[j])[i]);
        else      dsm[off[j] + i] = ((const bf16*)srcs[j])[i];
      }
    return;
  }
  if (is32) {
    float4 v = ((const float4*)src)[i4];
    short4v o;
    o[0] = f2b(v.x); o[1] = f2b(v.y); o[2] = f2b(v.z); o[3] = f2b(v.w);
    ((short4v*)dst)[i4] = o;
  } else {
    ((short4v*)dst)[i4] = ((const short4v*)src)[i4];
  }
}

// ---------------- QKV GEMM with FUSED RoPE epilogue (r13-validated) ----------------
__global__ __launch_bounds__(256, 1) void qkv_kernel(const bf16* __restrict__ X,
                                                     const bf16* __restrict__ Wqkv,
                                                     bf16* __restrict__ Q, bf16* __restrict__ K,
                                                     bf16* __restrict__ Vt,
                                                     const int* __restrict__ Wp) {
  int wave = threadIdx.x >> 6, lane = threadIdx.x & 63;
  int l15 = lane & 15, quad = lane >> 4;
  int m0 = (blockIdx.x * 4 + wave) * 64;
  int n0 = blockIdx.y * 64;
  const bf16* arow = X + (size_t)(m0 + l15) * CDIM + quad * 8;
  const bf16* brow = Wqkv + (size_t)(n0 + l15) * CDIM + quad * 8;
  f32x4 z = {0.f, 0.f, 0.f, 0.f};
  f32x4 acc[4][4];
#pragma unroll
  for (int j = 0; j < 4; ++j)
#pragma unroll
    for (int i = 0; i < 4; ++i) acc[j][i] = z;

  short8 a[4], b[4];
#pragma unroll
  for (int i = 0; i < 4; ++i) a[i] = ld8(arow + (size_t)i * 16 * CDIM);
#pragma unroll
  for (int j = 0; j < 4; ++j) b[j] = ld8(brow + (size_t)j * 16 * CDIM);
#pragma unroll
  for (int kk = 32; kk <= CDIM; kk += 32) {
    short8 an[4], bn[4];
    if (kk < CDIM) {
#pragma unroll
      for (int i = 0; i < 4; ++i) an[i] = ld8(arow + (size_t)i * 16 * CDIM + kk);
#pragma unroll
      for (int j = 0; j < 4; ++j) bn[j] = ld8(brow + (size_t)j * 16 * CDIM + kk);
    }
#pragma unroll
    for (int j = 0; j < 4; ++j)
#pragma unroll
      for (int i = 0; i < 4; ++i) acc[j][i] = mfma_bf16(b[j], a[i], acc[j][i]);
    if (kk < CDIM) {
#pragma unroll
      for (int i = 0; i < 4; ++i) a[i] = an[i];
#pragma unroll
      for (int j = 0; j < 4; ++j) b[j] = bn[j];
    }
  }

  int which = n0 >> 8, h = (n0 & 255) >> 6;
  if (which == 2) {
#pragma unroll
    for (int j = 0; j < 4; ++j) {
      int d0 = j * 16 + quad * 4;
#pragma unroll
      for (int i = 0; i < 4; ++i) {
        int gm = m0 + i * 16 + l15;
        int bb = gm / NSEQ, n = gm % NSEQ;
        int bh = bb * NHD + h;
#pragma unroll
        for (int r = 0; r < 4; ++r)
          Vt[((size_t)bh * DH + d0 + r) * NSEQ + n] = __float2bfloat16(acc[j][i][r]);
      }
    }
  } else {
    int Wv = Wp[0];
    if (Wv <= 0 || Wv > 65536) Wv = 48;
    bf16* dst = (which == 0) ? Q : K;
    const float cc = -0.28782313662425574f;  // -ln(10000)/32
    const float EC1 = 0.7498942434f, EC2 = 0.5623413252f, EC3 = 0.4216965034f;
#pragma unroll
    for (int i = 0; i < 4; ++i) {
      int gm = m0 + i * 16 + l15;
      int bb = gm / NSEQ, n = gm % NSEQ;
      int bh = bb * NHD + h;
      int py = n / Wv, px = n - py * Wv;
#pragma unroll
      for (int j = 0; j < 4; ++j) {
        int d0 = j * 16 + quad * 4;
        float pos = (d0 & 32) ? (float)px : (float)py;
        int base = d0 & 31;
        float fb = __expf(cc * (float)base);
        float f0 = fb, f1 = fb * EC1, f2 = fb * EC2, f3 = fb * EC3;
        float s0, c0, s1, c1, s2, c2, s3, c3;
        __sincosf(pos * f0, &s0, &c0);
        __sincosf(pos * f1, &s1, &c1);
        __sincosf(pos * f2, &s2, &c2);
        __sincosf(pos * f3, &s3, &c3);
        float a0 = acc[j][i][0], a1 = acc[j][i][1], a2 = acc[j][i][2], a3 = acc[j][i][3];
        short4v ov;
        ov[0] = f2b(a0 * c0 - a1 * s0);
        ov[1] = f2b(a1 * c1 + a0 * s1);
        ov[2] = f2b(a2 * c2 - a3 * s2);
        ov[3] = f2b(a3 * c3 + a2 * s3);
        *reinterpret_cast<short4v*>(dst + ((size_t)bh * NSEQ + n) * DH + d0) = ov;
      }
    }
  }
}

// ---------------- Flash attention (r8-validated: K-split + swizzled LDS) ----------------
__global__ __launch_bounds__(256, 4) void attn_kernel(const bf16* __restrict__ Q, const bf16* __restrict__ K,
                                                      const bf16* __restrict__ Vt, bf16* __restrict__ AO) {
  int bh = blockIdx.x, qt = blockIdx.y;
  int tid = threadIdx.x;
  int wave = tid >> 6, lane = tid & 63;
  int l15 = lane & 15, quad = lane >> 4;
  int qf = wave & 1;   // q half: rows [qf*32, qf*32+32)
  int ks = wave >> 1;  // k slice: cols [ks*32, ks*32+32) of each 64-tile
  int m0 = qt * 64 + qf * 32;
  const bf16* Qb = Q + (size_t)bh * NSEQ * DH;
  const bf16* Kb = K + (size_t)bh * NSEQ * DH;
  const bf16* Vb = Vt + (size_t)bh * DH * NSEQ;

  // [0,8K)+[8K,16K) = K double-buffer; [16K,24K)+[24K,32K) = V double-buffer.
  __shared__ __align__(16) char smem[32768];

  // staging: 256 threads cover 512 16B slots per tile (2 K + 2 V each)
  int r1 = tid >> 3, c1b = (tid & 7) * 16;   // row, byte slot
  int r1b = r1 + 32;

  // Q pre-scaled by 0.125 * log2(e) so p = exp2(s) directly
  const float QS = 0.18033688011112042f;
  short8 qa0 = ld8(Qb + (size_t)(m0 + l15) * DH + quad * 8);
  short8 qa1 = ld8(Qb + (size_t)(m0 + l15) * DH + 32 + quad * 8);
  short8 qb0 = ld8(Qb + (size_t)(m0 + 16 + l15) * DH + quad * 8);
  short8 qb1 = ld8(Qb + (size_t)(m0 + 16 + l15) * DH + 32 + quad * 8);
#pragma unroll
  for (int i = 0; i < 8; ++i) {
    qa0[i] = f2b(b2f(qa0[i]) * QS);
    qa1[i] = f2b(b2f(qa1[i]) * QS);
    qb0[i] = f2b(b2f(qb0[i]) * QS);
    qb1[i] = f2b(b2f(qb1[i]) * QS);
  }

  f32x4 z = {0.f, 0.f, 0.f, 0.f};
  f32x4 o[4] = {z, z, z, z};
  f32x4 o2[4] = {z, z, z, z};
  float l_run = 0.f, l_run2 = 0.f;

  // stage K/V tile 0
  *reinterpret_cast<short8*>(smem + swzb(r1, c1b))          = ld8(Kb + (size_t)r1 * DH + c1b / 2);
  *reinterpret_cast<short8*>(smem + swzb(r1b, c1b))         = ld8(Kb + (size_t)r1b * DH + c1b / 2);
  *reinterpret_cast<short8*>(smem + 16384 + swzb(r1, c1b))  = ld8(Vb + (size_t)r1 * NSEQ + c1b / 2);
  *reinterpret_cast<short8*>(smem + 16384 + swzb(r1b, c1b)) = ld8(Vb + (size_t)r1b * NSEQ + c1b / 2);
  __syncthreads();

  for (int it = 0; it < NSEQ / 64; ++it) {
    int cur = it & 1;
    bool more = (it + 1 < NSEQ / 64);

    // prefetch next K/V tile into registers (global)
    short8 kpA, kpB, vpA, vpB;
    if (more) {
      int kn = (it + 1) * 64;
      kpA = ld8(Kb + (size_t)(kn + r1) * DH + c1b / 2);
      kpB = ld8(Kb + (size_t)(kn + r1b) * DH + c1b / 2);
      vpA = ld8(Vb + (size_t)r1 * NSEQ + kn + c1b / 2);
      vpB = ld8(Vb + (size_t)r1b * NSEQ + kn + c1b / 2);
    }

    const char* kb = smem + cur * 8192;
    const char* vb = smem + 16384 + cur * 8192;

    // QK^T for this wave's 32 k-rows x 32 q-rows
    f32x4 s[2], s2[2];
#pragma unroll
    for (int kt = 0; kt < 2; ++kt) {
      int krow = ks * 32 + kt * 16 + l15;
      short8 kf0 = *reinterpret_cast<const short8*>(kb + swzb(krow, quad * 16));
      short8 kf1 = *reinterpret_cast<const short8*>(kb + swzb(krow, quad * 16 + 64));
      s[kt] = mfma_bf16(kf0, qa0, z);
      s[kt] = mfma_bf16(kf1, qa1, s[kt]);
      s2[kt] = mfma_bf16(kf0, qb0, z);
      s2[kt] = mfma_bf16(kf1, qb1, s2[kt]);
    }

    // exp2 + in-register P->B-frag redistribution (no LDS)
    unsigned int A0, B0, A1, B1, C0, D0, C1, D1;
    {
      float p00 = EXP2F(s[0][0]), p01 = EXP2F(s[0][1]), p02 = EXP2F(s[0][2]), p03 = EXP2F(s[0][3]);
      float p10 = EXP2F(s[1][0]), p11 = EXP2F(s[1][1]), p12 = EXP2F(s[1][2]), p13 = EXP2F(s[1][3]);
      l_run += ((p00 + p01) + (p02 + p03)) + ((p10 + p11) + (p12 + p13));
      asm("v_cvt_pk_bf16_f32 %0, %1, %2" : "=v"(A0) : "v"(p00), "v"(p01));
      asm("v_cvt_pk_bf16_f32 %0, %1, %2" : "=v"(B0) : "v"(p02), "v"(p03));
      asm("v_cvt_pk_bf16_f32 %0, %1, %2" : "=v"(A1) : "v"(p10), "v"(p11));
      asm("v_cvt_pk_bf16_f32 %0, %1, %2" : "=v"(B1) : "v"(p12), "v"(p13));
      float q00 = EXP2F(s2[0][0]), q01 = EXP2F(s2[0][1]), q02 = EXP2F(s2[0][2]), q03 = EXP2F(s2[0][3]);
      float q10 = EXP2F(s2[1][0]), q11 = EXP2F(s2[1][1]), q12 = EXP2F(s2[1][2]), q13 = EXP2F(s2[1][3]);
      l_run2 += ((q00 + q01) + (q02 + q03)) + ((q10 + q11) + (q12 + q13));
      asm("v_cvt_pk_bf16_f32 %0, %1, %2" : "=v"(C0) : "v"(q00), "v"(q01));
      asm("v_cvt_pk_bf16_f32 %0, %1, %2" : "=v"(D0) : "v"(q02), "v"(q03));
      asm("v_cvt_pk_bf16_f32 %0, %1, %2" : "=v"(C1) : "v"(q10), "v"(q11));
      asm("v_cvt_pk_bf16_f32 %0, %1, %2" : "=v"(D1) : "v"(q12), "v"(q13));
    }
    asm("v_permlane32_swap_b32 %0, %1" : "+v"(A0), "+v"(A1));
    asm("v_permlane16_swap_b32 %0, %1" : "+v"(A0), "+v"(A1));
    asm("v_permlane32_swap_b32 %0, %1" : "+v"(B0), "+v"(B1));
    asm("v_permlane16_swap_b32 %0, %1" : "+v"(B0), "+v"(B1));
    asm("v_permlane32_swap_b32 %0, %1" : "+v"(C0), "+v"(C1));
    asm("v_permlane16_swap_b32 %0, %1" : "+v"(C0), "+v"(C1));
    asm("v_permlane32_swap_b32 %0, %1" : "+v"(D0), "+v"(D1));
    asm("v_permlane16_swap_b32 %0, %1" : "+v"(D0), "+v"(D1));

    u32x4 wA; wA[0] = A0; wA[1] = B0; wA[2] = A1; wA[3] = B1;
    u32x4 wB; wB[0] = C0; wB[1] = D0; wB[2] = C1; wB[3] = D1;
    short8 pfA = *reinterpret_cast<short8*>(&wA);
    short8 pfB = *reinterpret_cast<short8*>(&wB);

    // PV for this wave's 32 k-cols (partial o over the k-slice)
#pragma unroll
    for (int t = 0; t < 4; ++t) {
      short8 vf = *reinterpret_cast<const short8*>(vb + swzb(t * 16 + l15, ks * 64 + quad * 16));
      o[t] = mfma_bf16(vf, pfA, o[t]);
      o2[t] = mfma_bf16(vf, pfB, o2[t]);
    }

    if (more) {
      char* kn_ = smem + (1 - cur) * 8192;
      char* vn_ = smem + 16384 + (1 - cur) * 8192;
      *reinterpret_cast<short8*>(kn_ + swzb(r1, c1b))  = kpA;
      *reinterpret_cast<short8*>(kn_ + swzb(r1b, c1b)) = kpB;
      *reinterpret_cast<short8*>(vn_ + swzb(r1, c1b))  = vpA;
      *reinterpret_cast<short8*>(vn_ + swzb(r1b, c1b)) = vpB;
    }
    __syncthreads();
  }

  // ---- cross-kslice combine via LDS scratch (smem is dead now) ----
  float* scr = (float*)smem;
  int slot = qf * 64 + lane;  // wave2 pairs wave0 (qf=0), wave3 pairs wave1
  if (ks == 1) {
    float* p = scr + slot * 36;
#pragma unroll
    for (int t = 0; t < 4; ++t) {
      *reinterpret_cast<f32x4*>(p + t * 4) = o[t];
      *reinterpret_cast<f32x4*>(p + 16 + t * 4) = o2[t];
    }
    p[32] = l_run;
    p[33] = l_run2;
  }
  __syncthreads();
  if (ks == 0) {
    float* p = scr + slot * 36;
#pragma unroll
    for (int t = 0; t < 4; ++t) {
      f32x4 pa = *reinterpret_cast<f32x4*>(p + t * 4);
      f32x4 pb2 = *reinterpret_cast<f32x4*>(p + 16 + t * 4);
#pragma unroll
      for (int r = 0; r < 4; ++r) {
        o[t][r] += pa[r];
        o2[t][r] += pb2[r];
      }
    }
    l_run += p[32];
    l_run2 += p[33];

    l_run += __shfl_xor(l_run, 16);
    l_run += __shfl_xor(l_run, 32);
    l_run2 += __shfl_xor(l_run2, 16);
    l_run2 += __shfl_xor(l_run2, 32);
    float inv = 1.f / l_run;
    float inv2 = 1.f / l_run2;
    int b = bh >> 2, h = bh & 3;
    bf16* orow = AO + ((size_t)b * NSEQ + (m0 + l15)) * CDIM + h * DH;
    bf16* orow2 = AO + ((size_t)b * NSEQ + (m0 + 16 + l15)) * CDIM + h * DH;
#pragma unroll
    for (int t = 0; t < 4; ++t) {
      short4v ov, ov2;
#pragma unroll
      for (int r = 0; r < 4; ++r) {
        ov[r] = f2b(o[t][r] * inv);
        ov2[r] = f2b(o2[t][r] * inv2);
      }
      *reinterpret_cast<short4v*>(orow + t * 16 + quad * 4) = ov;
      *reinterpret_cast<short4v*>(orow2 + t * 16 + quad * 4) = ov2;
    }
  }
}

// ---------------- Canonical 128-tile GEMM ----------------
// EPI==1 (FC1 GELU) epilogue changed: cvt_pk + permlane32/16_swap (attn-r4-
// validated index transform: 16m+4quad+r -> 8quad packing) so each lane
// stores 16 contiguous bytes -> 64B-contiguous sector-aligned spans per row,
// fixing the measured 2.3x WRITE_SIZE amplification of the scattered 8B
// stores. EPI 0/2 unchanged.
template <int KD, int EPI, int TI>
__global__ __launch_bounds__(256) void gemm128(const bf16* __restrict__ A, const bf16* __restrict__ Wm,
                                               const bf16* __restrict__ bias, const bf16* __restrict__ res,
                                               bf16* __restrict__ outp, int NC) {
  constexpr int KS = KD / 32;
  constexpr int AR = TI * 32;
  int tid = threadIdx.x;
  int wave = tid >> 6, lane = tid & 63;
  int l15 = lane & 15, quad = lane >> 4;
  int wm = (wave >> 1) * (TI * 16);
  int wn = (wave & 1) * 64;
  int m0 = blockIdx.x * AR;
  int n0 = blockIdx.y * 128;

  __shared__ __align__(16) bf16 abuf[2][AR * 40];
  __shared__ __align__(16) bf16 bbuf[2][128 * 40];

  int sr = tid >> 2, sc = (tid & 3) * 8;

  const bf16* ag[TI / 2];
#pragma unroll
  for (int u = 0; u < TI / 2; ++u) ag[u] = A + (size_t)(m0 + sr + u * 64) * KD + sc;
  const bf16* bg0 = Wm + (size_t)(n0 + sr) * KD + sc;
  const bf16* bg1 = Wm + (size_t)(n0 + 64 + sr) * KD + sc;

  f32x4 z = {0.f, 0.f, 0.f, 0.f};
  f32x4 acc[4][TI];
#pragma unroll
  for (int j = 0; j < 4; ++j)
#pragma unroll
    for (int i = 0; i < TI; ++i) acc[j][i] = z;

#pragma unroll
  for (int u = 0; u < TI / 2; ++u)
    *reinterpret_cast<short8*>(abuf[0] + (sr + u * 64) * 40 + sc) = ld8(ag[u]);
  *reinterpret_cast<short8*>(bbuf[0] + sr * 40 + sc) = ld8(bg0);
  *reinterpret_cast<short8*>(bbuf[0] + (64 + sr) * 40 + sc) = ld8(bg1);
  __syncthreads();

  for (int s = 0; s < KS; ++s) {
    int cur = s & 1;
    bool more = (s + 1 < KS);
    short8 anx[TI / 2], bnx0, bnx1;
    if (more) {
#pragma unroll
      for (int u = 0; u < TI / 2; ++u) anx[u] = ld8(ag[u] + (s + 1) * 32);
      bnx0 = ld8(bg0 + (s + 1) * 32);
      bnx1 = ld8(bg1 + (s + 1) * 32);
    }
    short8 af[TI], bf_[4];
#pragma unroll
    for (int i = 0; i < TI; ++i)
      af[i] = lds8(abuf[cur] + (size_t)(wm + i * 16 + l15) * 40 + quad * 8);
#pragma unroll
    for (int j = 0; j < 4; ++j)
      bf_[j] = lds8(bbuf[cur] + (size_t)(wn + j * 16 + l15) * 40 + quad * 8);
#pragma unroll
    for (int j = 0; j < 4; ++j)
#pragma unroll
      for (int i = 0; i < TI; ++i)
        acc[j][i] = mfma_bf16(bf_[j], af[i], acc[j][i]);
    if (more) {
#pragma unroll
      for (int u = 0; u < TI / 2; ++u)
        *reinterpret_cast<short8*>(abuf[1 - cur] + (sr + u * 64) * 40 + sc) = anx[u];
      *reinterpret_cast<short8*>(bbuf[1 - cur] + sr * 40 + sc) = bnx0;
      *reinterpret_cast<short8*>(bbuf[1 - cur] + (64 + sr) * 40 + sc) = bnx1;
    }
    __syncthreads();
  }

  if (EPI == 1) {
    // GELU epilogue with 16B-contiguous lane stores
#pragma unroll
    for (int jp = 0; jp < 2; ++jp) {
      int j0 = jp * 2, j1 = jp * 2 + 1;
      short4v blA = *reinterpret_cast<const short4v*>(bias + n0 + wn + j0 * 16 + quad * 4);
      short4v blB = *reinterpret_cast<const short4v*>(bias + n0 + wn + j1 * 16 + quad * 4);
      float bbA[4], bbB[4];
#pragma unroll
      for (int r = 0; r < 4; ++r) { bbA[r] = b2f(blA[r]); bbB[r] = b2f(blB[r]); }
#pragma unroll
      for (int i = 0; i < TI; ++i) {
        float g0[4], g1v[4];
#pragma unroll
        for (int r = 0; r < 4; ++r) {
          float hv = acc[j0][i][r] + bbA[r];
          g0[r] = 0.5f * hv * (1.f + erff(hv * 0.70710678118f));
          float hw = acc[j1][i][r] + bbB[r];
          g1v[r] = 0.5f * hw * (1.f + erff(hw * 0.70710678118f));
        }
        unsigned int A0, B0, A1, B1;
        asm("v_cvt_pk_bf16_f32 %0, %1, %2" : "=v"(A0) : "v"(g0[0]), "v"(g0[1]));
        asm("v_cvt_pk_bf16_f32 %0, %1, %2" : "=v"(B0) : "v"(g0[2]), "v"(g0[3]));
        asm("v_cvt_pk_bf16_f32 %0, %1, %2" : "=v"(A1) : "v"(g1v[0]), "v"(g1v[1]));
        asm("v_cvt_pk_bf16_f32 %0, %1, %2" : "=v"(B1) : "v"(g1v[2]), "v"(g1v[3]));
        asm("v_permlane32_swap_b32 %0, %1" : "+v"(A0), "+v"(A1));
        asm("v_permlane16_swap_b32 %0, %1" : "+v"(A0), "+v"(A1));
        asm("v_permlane32_swap_b32 %0, %1" : "+v"(B0), "+v"(B1));
        asm("v_permlane16_swap_b32 %0, %1" : "+v"(B0), "+v"(B1));
        u32x4 w; w[0] = A0; w[1] = B0; w[2] = A1; w[3] = B1;
        size_t idx = (size_t)(m0 + wm + i * 16 + l15) * NC + n0 + wn + jp * 32 + quad * 8;
        *reinterpret_cast<u32x4*>(outp + idx) = w;
      }
    }
  } else {
#pragma unroll
    for (int j = 0; j < 4; ++j) {
      int col0 = n0 + wn + j * 16 + quad * 4;
      float bb4[4];
      if (EPI != 0) {
        short4v bl = *reinterpret_cast<const short4v*>(bias + col0);
#pragma unroll
        for (int r = 0; r < 4; ++r) bb4[r] = b2f(bl[r]);
      }
#pragma unroll
      for (int i = 0; i < TI; ++i) {
        size_t idx = (size_t)(m0 + wm + i * 16 + l15) * NC + col0;
        short4v ov;
        if (EPI == 0) {
          short4v rl = *reinterpret_cast<const short4v*>(res + idx);
#pragma unroll
          for (int r = 0; r < 4; ++r) ov[r] = f2b(acc[j][i][r] + b2f(rl[r]));
        } else {
          short4v rl = *reinterpret_cast<const short4v*>(res + idx);
#pragma unroll
          for (int r = 0; r < 4; ++r) ov[r] = f2b(acc[j][i][r] + bb4[r] + b2f(rl[r]));
        }
        *reinterpret_cast<short4v*>(outp + idx) = ov;
      }
    }
  }
}

// ---------------- GEMM (NC=256) with residual + FUSED LayerNorm epilogue ----------------
template <int KD, int HASBIAS, int FINAL>
__global__ __launch_bounds__(256) void gemm_ln(const bf16* __restrict__ A, const bf16* __restrict__ Wm,
                                               const bf16* __restrict__ bias, const bf16* __restrict__ res,
                                               const bf16* __restrict__ g, const bf16* __restrict__ bv,
                                               void* __restrict__ outp, const int* __restrict__ flag) {
  constexpr int KS = KD / 32;
  int tid = threadIdx.x;
  int wave = tid >> 6, lane = tid & 63;
  int l15 = lane & 15, quad = lane >> 4;
  int wn = wave * 64;
  int m0 = blockIdx.x * 32;
  int is32 = FINAL ? flag[0] : 0;

  __shared__ __align__(16) bf16 abuf[2][32 * 40];
  __shared__ __align__(16) bf16 bbuf[2][256 * 40];
  __shared__ float red[4][32][2];

  int sr = tid >> 2, sc = (tid & 3) * 8;      // B: rows sr+u*64, u=0..3
  bool doA = tid < 128;
  int ra = tid >> 2, ca = (tid & 3) * 8;      // A: rows 0..31 (tid<128)

  const bf16* ag = A + (size_t)(m0 + ra) * KD + ca;
  const bf16* bg[4];
#pragma unroll
  for (int u = 0; u < 4; ++u) bg[u] = Wm + (size_t)(sr + u * 64) * KD + sc;

  f32x4 z = {0.f, 0.f, 0.f, 0.f};
  f32x4 acc[4][2];
#pragma unroll
  for (int j = 0; j < 4; ++j)
#pragma unroll
    for (int i = 0; i < 2; ++i) acc[j][i] = z;

  if (doA) *reinterpret_cast<short8*>(abuf[0] + ra * 40 + ca) = ld8(ag);
#pragma unroll
  for (int u = 0; u < 4; ++u)
    *reinterpret_cast<short8*>(bbuf[0] + (sr + u * 64) * 40 + sc) = ld8(bg[u]);
  __syncthreads();

  for (int s = 0; s < KS; ++s) {
    int cur = s & 1;
    bool more = (s + 1 < KS);
    short8 anx, bnx[4];
    if (more) {
      if (doA) anx = ld8(ag + (s + 1) * 32);
#pragma unroll
      for (int u = 0; u < 4; ++u) bnx[u] = ld8(bg[u] + (s + 1) * 32);
    }
    short8 af[2], bf_[4];
#pragma unroll
    for (int i = 0; i < 2; ++i)
      af[i] = lds8(abuf[cur] + (size_t)(i * 16 + l15) * 40 + quad * 8);
#pragma unroll
    for (int j = 0; j < 4; ++j)
      bf_[j] = lds8(bbuf[cur] + (size_t)(wn + j * 16 + l15) * 40 + quad * 8);
#pragma unroll
    for (int j = 0; j < 4; ++j)
#pragma unroll
      for (int i = 0; i < 2; ++i)
        acc[j][i] = mfma_bf16(bf_[j], af[i], acc[j][i]);
    if (more) {
      if (doA) *reinterpret_cast<short8*>(abuf[1 - cur] + ra * 40 + ca) = anx;
#pragma unroll
      for (int u = 0; u < 4; ++u)
        *reinterpret_cast<short8*>(bbuf[1 - cur] + (sr + u * 64) * 40 + sc) = bnx[u];
    }
    __syncthreads();
  }

  // ---- epilogue: bias + residual, then fused LayerNorm over the full row ----
  float bb[4][4];
  if (HASBIAS) {
#pragma unroll
    for (int j = 0; j < 4; ++j) {
      short4v bl = *reinterpret_cast<const short4v*>(bias + wn + j * 16 + quad * 4);
#pragma unroll
      for (int r = 0; r < 4; ++r) bb[j][r] = b2f(bl[r]);
    }
  }
  float vals[2][4][4];
  float s0 = 0.f, q0 = 0.f, s1 = 0.f, q1 = 0.f;
#pragma unroll
  for (int i = 0; i < 2; ++i) {
    int row = m0 + i * 16 + l15;
#pragma unroll
    for (int j = 0; j < 4; ++j) {
      int col0 = wn + j * 16 + quad * 4;
      short4v rl = *reinterpret_cast<const short4v*>(res + (size_t)row * CDIM + col0);
#pragma unroll
      for (int r = 0; r < 4; ++r) {
        float v = acc[j][i][r] + (HASBIAS ? bb[j][r] : 0.f) + b2f(rl[r]);
        vals[i][j][r] = v;
        if (i == 0) { s0 += v; q0 += v * v; }
        else        { s1 += v; q1 += v * v; }
      }
    }
  }
  s0 += __shfl_xor(s0, 16); s0 += __shfl_xor(s0, 32);
  q0 += __shfl_xor(q0, 16); q0 += __shfl_xor(q0, 32);
  s1 += __shfl_xor(s1, 16); s1 += __shfl_xor(s1, 32);
  q1 += __shfl_xor(q1, 16); q1 += __shfl_xor(q1, 32);
  if (quad == 0) {
    red[wave][l15][0] = s0;      red[wave][l15][1] = q0;
    red[wave][16 + l15][0] = s1; red[wave][16 + l15][1] = q1;
  }
  __syncthreads();

#pragma unroll
  for (int i = 0; i < 2; ++i) {
    int rl_ = i * 16 + l15;
    float S = 0.f, Q = 0.f;
#pragma unroll
    for (int w = 0; w < 4; ++w) { S += red[w][rl_][0]; Q += red[w][rl_][1]; }
    float mu = S * (1.f / CDIM);
    float var = Q * (1.f / CDIM) - mu * mu;
    float rstd = rsqrtf(var + 1e-5f);
    int row = m0 + i * 16 + l15;
#pragma unroll
    for (int j = 0; j < 4; ++j) {
      int col0 = wn + j * 16 + quad * 4;
      short4v gl = *reinterpret_cast<const short4v*>(g + col0);
      short4v bl2 = *reinterpret_cast<const short4v*>(bv + col0);
      size_t idx = (size_t)row * CDIM + col0;
      if (FINAL && is32) {
        float4 ov;
        ov.x = (vals[i][j][0] - mu) * rstd * b2f(gl[0]) + b2f(bl2[0]);
        ov.y = (vals[i][j][1] - mu) * rstd * b2f(gl[1]) + b2f(bl2[1]);
        ov.z = (vals[i][j][2] - mu) * rstd * b2f(gl[2]) + b2f(bl2[2]);
        ov.w = (vals[i][j][3] - mu) * rstd * b2f(gl[3]) + b2f(bl2[3]);
        *reinterpret_cast<float4*>((float*)outp + idx) = ov;
      } else {
        short4v ov;
#pragma unroll
        for (int r = 0; r < 4; ++r)
          ov[r] = f2b((vals[i][j][r] - mu) * rstd * b2f(gl[r]) + b2f(bl2[r]));
        *reinterpret_cast<short4v*>((bf16*)outp + idx) = ov;
      }
    }
  }
}

extern "C" void kernel_launch(void* const* d_in, const int* in_sizes, int n_in,
                              void* d_out, int out_size, void* d_ws, size_t ws_size,
                              hipStream_t stream) {
  const int* Wp = (const int*)d_in[12];

  char* ws = (char*)d_ws;
  const size_t SZ = 4718592;  // 2304*4*256 bf16 bytes
  bf16* Qc  = (bf16*)(ws + 0 * SZ);
  bf16* Kc  = (bf16*)(ws + 1 * SZ);
  bf16* Vt  = (bf16*)(ws + 2 * SZ);
  bf16* AO  = (bf16*)(ws + 3 * SZ);
  bf16* F   = (bf16*)(ws + 4 * SZ);
  bf16* xc  = (bf16*)(ws + 6 * SZ);
  bf16* G   = (bf16*)(ws + 0);              // overlays Qc..AO (4*SZ exactly)
  bf16* Wqkvc  = (bf16*)(ws + 7 * SZ);
  bf16* Wprojc = (bf16*)(ws + 7 * SZ + 393216);
  bf16* W1c    = (bf16*)(ws + 7 * SZ + 524288);
  bf16* W2c    = (bf16*)(ws + 7 * SZ + 1048576);
  bf16* smallc = (bf16*)(ws + 7 * SZ + 1572864);
  bf16* g1c  = smallc + 0;
  bf16* b1c  = smallc + 256;
  bf16* g2c  = smallc + 512;
  bf16* b2c  = smallc + 768;
  bf16* bf1c = smallc + 1024;
  bf16* bf2c = smallc + 2048;
  int*  flagp = (int*)(ws + 7 * SZ + 1581568);

  detect_kernel<<<1, 256, 0, stream>>>(d_in[0], flagp);
  cvt_all_kernel<<<3073, 256, 0, stream>>>(d_in[0], d_in[1], d_in[2], d_in[7], d_in[9],
                                           d_in[3], d_in[4], d_in[5], d_in[6], d_in[8], d_in[10],
                                           xc, Wqkvc, Wprojc, W1c, W2c, smallc, flagp);

  qkv_kernel<<<dim3(36, 12), 256, 0, stream>>>(xc, Wqkvc, Qc, Kc, Vt, Wp);
  attn_kernel<<<dim3(16, 36), 256, 0, stream>>>(Qc, Kc, Vt, AO);
  // proj + residual + LN1 -> F (bf16)
  gemm_ln<256, 0, 0><<<288, 256, 0, stream>>>(AO, Wprojc, nullptr, xc, g1c, b1c, F, flagp);
  // FC1 + bias + GELU -> G (contiguous-store epilogue)
  gemm128<256, 1, 4><<<dim3(72, 8), 256, 0, stream>>>(F, W1c, bf1c, nullptr, G, 1024);
  // FC2 + bias + residual(F) + LN2 -> d_out (flag dtype)
  gemm_ln<1024, 1, 1><<<288, 256, 0, stream>>>(G, W2c, bf2c, F, g2c, b2c, d_out, flagp);
}